// Round 7
// baseline (235.907 us; speedup 1.0000x reference)
//
#include <hip/hip_runtime.h>
#include <stdint.h>

#define BATCH 8192   // Gram K dimension
#define DIM   2048   // Gram M and N

typedef unsigned char  u8;
typedef unsigned short u16;
typedef unsigned int   u32;

using v8i  = __attribute__((ext_vector_type(8)))  int;
using v16f = __attribute__((ext_vector_type(16))) float;

#if __has_builtin(__builtin_amdgcn_cvt_scalef32_pk_fp4_f32)
#define HW_FP4 1
#endif

// async global->LDS, 16B per lane; dest must be wave-uniform base + lane*16.
__device__ __forceinline__ void gl_lds16(const void* g, void* l) {
  __builtin_amdgcn_global_load_lds(
      (const __attribute__((address_space(1))) u32*)g,
      (__attribute__((address_space(3))) u32*)l, 16, 0, 0);
}

// Fallback f32 -> fp4 e2m1 nibble of (64*x), round-to-nearest.
__device__ __forceinline__ u32 nib4(float x) {
  float xs = x * 64.0f;
  float a  = fabsf(xs);
  u32 n = (u32)(a >= 0.25f) + (u32)(a >= 0.75f) + (u32)(a >= 1.25f) +
          (u32)(a >= 1.75f) + (u32)(a >= 2.5f)  + (u32)(a >= 3.5f)  +
          (u32)(a >= 5.0f);
  return n | (xs < 0.0f ? 8u : 0u);
}

// Pack 4 floats (already in quant domain after *64) into 4 e2m1 nibbles (u16).
__device__ __forceinline__ u16 pack4_fp4(float a, float b, float c, float d) {
#ifdef HW_FP4
  // HW MX quantizer; scale=1.0f makes multiply-vs-divide semantics moot.
  u32 w = __builtin_amdgcn_cvt_scalef32_pk_fp4_f32(0u,  a * 64.0f, b * 64.0f, 1.0f, 0);
  w     = __builtin_amdgcn_cvt_scalef32_pk_fp4_f32(w,   c * 64.0f, d * 64.0f, 1.0f, 1);
  return (u16)w;   // nibble order within byte may differ from soft path ->
                   // pure k-permutation, cancels in the Gram dot.
#else
  return (u16)(nib4(a) | (nib4(b) << 4) | (nib4(c) << 8) | (nib4(d) << 12));
#endif
}

// ---------------------------------------------------------------------------
// Kernel 1: fused transpose + f32->fp4(e2m1, pre-scaled by 64).
// src [8192 b][2048 d] f32 -> dst [2048 d][8192 b-fp4] (4096 B/row).
// Structure identical to round 6 (proven); quantizer swapped to HW cvt.
// Block 0 also zero-inits acc + ticket (stream-ordered before dot).
// ---------------------------------------------------------------------------
__global__ __launch_bounds__(256) void tcvt_fp4(
    const float* __restrict__ L, const float* __restrict__ T,
    u8* __restrict__ X, u8* __restrict__ Y,
    float* __restrict__ acc, u32* __restrict__ cnt)
{
  __shared__ u16 ls[64 * 68];   // [d][64 u16 payload + 4 pad]

  const int tid = threadIdx.x;
  if (blockIdx.x == 0 && tid == 0) { *acc = 0.0f; *cnt = 0u; }

  int id = blockIdx.x;
  const float* src;
  u8* dst;
  if (id < 1024) { src = L; dst = X; }
  else           { src = T; dst = Y; id -= 1024; }
  const int d0 = (id & 31) * 64;
  const int b0 = (id >> 5) * 256;

  const int s  = tid & 15;          // d-slot (d = 4s..4s+3)
  const int g  = tid >> 4;          // b row-group
  const int sw = s & 12;
#pragma unroll
  for (int j = 0; j < 4; ++j) {
    const int brow = j * 64 + g * 4;
    float4 f[4];
#pragma unroll
    for (int r = 0; r < 4; ++r)
      f[r] = *(const float4*)(src + (size_t)(b0 + brow + r) * DIM + d0 + s * 4);
    const int w = (j * 16 + g) ^ sw;   // u16 column 0..63
    const float* fp[4] = {(const float*)&f[0], (const float*)&f[1],
                          (const float*)&f[2], (const float*)&f[3]};
#pragma unroll
    for (int i = 0; i < 4; ++i)
      ls[(s * 4 + i) * 68 + w] = pack4_fp4(fp[0][i], fp[1][i], fp[2][i], fp[3][i]);
  }
  __syncthreads();

  // Phase B: row d has 64 u16 = 128 B of fp4; u16-column swizzle was on bits
  // 2..3 with mask s&12 -> group-of-4 swizzle gsw = (d>>4)&3.
#pragma unroll
  for (int j2 = 0; j2 < 2; ++j2) {
    const int d   = (tid >> 3) + j2 * 32;
    const int o8  = tid & 7;
    const int gsw = (d >> 4) & 3;
    const int g1  = (2 * o8)     ^ gsw;
    const int g2  = (2 * o8 + 1) ^ gsw;
    uint2 a = *(const uint2*)&ls[d * 68 + g1 * 4];
    uint2 b = *(const uint2*)&ls[d * 68 + g2 * 4];
    uint4 v = {a.x, a.y, b.x, b.y};
    *(uint4*)(dst + (size_t)(d0 + d) * (BATCH / 2) + (b0 >> 1) + o8 * 16) = v;
  }
}

// ---------------------------------------------------------------------------
// Kernel 2: Gram tile, materialized, MX-fp4, double-buffered LDS (round-6
// proven, UNCHANGED for attribution). 512 blocks = 2 grams x 256 tiles,
// 2 blocks/CU. mfma_scale_f32_32x32x64_f8f6f4 cbsz=blgp=4, payload v[0:3].
// ---------------------------------------------------------------------------
__global__ __launch_bounds__(256, 2) void gram_fp4(
    const u8* __restrict__ X, const u8* __restrict__ Y,
    float* __restrict__ Gx, float* __restrict__ Gy)
{
  __shared__ u8 ls[2][2][8192];   // [buf][panel I/J][128 rows x 64 B]

  const int tid = threadIdx.x;
  const int bid = blockIdx.x;
  const int t   = bid & 255;
  const u8*  src = (bid < 256) ? X : Y;
  float*     dst = (bid < 256) ? Gx : Gy;
  const int i0  = (t >> 4) * 128;
  const int j0  = (t & 15) * 128;

  const int wave = tid >> 6;
  const int lane = tid & 63;
  const int wr = (wave >> 1) * 64;
  const int wc = (wave & 1) * 64;
  const int lr = lane & 31;
  const int kh = lane >> 5;

  u32 sdst[2], soi[2], soj[2];
#pragma unroll
  for (int rr = 0; rr < 2; ++rr) {
    const int li  = rr * 256 + tid;
    const int row = li >> 2;
    const int p   = li & 3;
    const int gc  = p ^ (row & 3);
    sdst[rr] = (u32)(row * 64 + p * 16);
    soi[rr]  = (u32)(i0 + row) * (BATCH / 2) + gc * 16;
    soj[rr]  = (u32)(j0 + row) * (BATCH / 2) + gc * 16;
  }

  u32 fa[2][2], fb[2][2];
#pragma unroll
  for (int h = 0; h < 2; ++h) {
    const int ra = wr + h * 32 + lr;
    const int rb = wc + h * 32 + lr;
#pragma unroll
    for (int ks = 0; ks < 2; ++ks) {
      const int c = 2 * ks + kh;
      fa[h][ks] = (u32)(ra * 64 + (c ^ (ra & 3)) * 16);
      fb[h][ks] = (u32)(rb * 64 + (c ^ (rb & 3)) * 16);
    }
  }

  v16f acc[2][2] = {};
  const int sc = 0x7F7F7F7F;          // e8m0 = 127 -> scale 1.0

#pragma unroll
  for (int rr = 0; rr < 2; ++rr) {
    gl_lds16(src + soi[rr], &ls[0][0][sdst[rr]]);
    gl_lds16(src + soj[rr], &ls[0][1][sdst[rr]]);
  }

  for (int it = 0; it < 64; ++it) {
    __syncthreads();
    const int buf = it & 1;
    if (it < 63) {
      const u32 k1 = (u32)(it + 1) * 64;
#pragma unroll
      for (int rr = 0; rr < 2; ++rr) {
        gl_lds16(src + soi[rr] + k1, &ls[buf ^ 1][0][sdst[rr]]);
        gl_lds16(src + soj[rr] + k1, &ls[buf ^ 1][1][sdst[rr]]);
      }
    }
    const u8* pI = ls[buf][0];
    const u8* pJ = ls[buf][1];
#pragma unroll
    for (int ks = 0; ks < 2; ++ks) {
      v8i a[2], b[2];
#pragma unroll
      for (int h = 0; h < 2; ++h) {
        int4 pa = *(const int4*)&pI[fa[h][ks]];
        a[h] = (v8i){pa.x, pa.y, pa.z, pa.w, 0, 0, 0, 0};
        int4 pb = *(const int4*)&pJ[fb[h][ks]];
        b[h] = (v8i){pb.x, pb.y, pb.z, pb.w, 0, 0, 0, 0};
      }
#pragma unroll
      for (int h = 0; h < 2; ++h)
#pragma unroll
        for (int hc = 0; hc < 2; ++hc)
          acc[h][hc] = __builtin_amdgcn_mfma_scale_f32_32x32x64_f8f6f4(
              a[h], b[hc], acc[h][hc], /*cbsz=fp4*/ 4, /*blgp=fp4*/ 4,
              0, sc, 0, sc);
    }
  }

  float4* o = (float4*)(dst + (size_t)t * 16384);
#pragma unroll
  for (int h = 0; h < 2; ++h)
#pragma unroll
    for (int hc = 0; hc < 2; ++hc)
#pragma unroll
      for (int r4 = 0; r4 < 4; ++r4) {
        float4 v = {acc[h][hc][r4 * 4 + 0], acc[h][hc][r4 * 4 + 1],
                    acc[h][hc][r4 * 4 + 2], acc[h][hc][r4 * 4 + 3]};
        o[((h * 2 + hc) * 4 + r4) * 256 + tid] = v;
      }
}

// ---------------------------------------------------------------------------
// Kernel 3: elementwise dot of the two Grams + fused finalize (ticket).
// ---------------------------------------------------------------------------
__global__ __launch_bounds__(256) void dot_kernel(
    const float4* __restrict__ Gx, const float4* __restrict__ Gy,
    float* __restrict__ d_acc, u32* __restrict__ d_cnt,
    float* __restrict__ out)
{
  __shared__ float red[4];
  const int tid  = threadIdx.x;
  const int lane = tid & 63;
  const int i0   = blockIdx.x * 256 + tid;
  float s = 0.0f;
#pragma unroll
  for (int j = 0; j < 4; ++j) {
    float4 a = Gx[i0 + j * 262144];
    float4 b = Gy[i0 + j * 262144];
    s += a.x * b.x + a.y * b.y + a.z * b.z + a.w * b.w;
  }
#pragma unroll
  for (int off = 32; off > 0; off >>= 1)
    s += __shfl_down(s, off);
  if (lane == 0) red[tid >> 6] = s;
  __syncthreads();
  if (tid == 0) {
    atomicAdd(d_acc, red[0] + red[1] + red[2] + red[3]);
    __threadfence();
    const u32 old = atomicAdd(d_cnt, 1u);
    if (old == 1023u) {                      // last of 1024 blocks
      float S   = atomicAdd(d_acc, 0.0f);    // device-coherent read
      // fidelity = S / (B^2 * 64^4) = S * 2^-50
      float fid = S * 0x1.0p-50f;
      fid = fminf(fmaxf(fid, 0.0f), 1.0f);
      *out = 0.1f * fabsf(fid - 0.95f);
    }
  }
}

extern "C" void kernel_launch(void* const* d_in, const int* in_sizes, int n_in,
                              void* d_out, int out_size, void* d_ws, size_t ws_size,
                              hipStream_t stream) {
  const float* L = (const float*)d_in[0];
  const float* T = (const float*)d_in[1];
  float* out = (float*)d_out;

  const size_t NF4 = (size_t)BATCH * DIM / 2;    // 8,388,608 B per fp4 tensor
  const size_t GEL = (size_t)DIM * DIM;          // 4,194,304 floats per Gram
  u8*    X   = (u8*)d_ws;
  u8*    Y   = (u8*)d_ws + NF4;
  float* Gx  = (float*)((char*)d_ws + 2 * NF4);
  float* Gy  = Gx + GEL;
  float* acc = Gy + GEL;
  u32*   cnt = (u32*)(acc + 1);

  tcvt_fp4<<<2048, 256, 0, stream>>>(L, T, X, Y, acc, cnt);
  gram_fp4<<<512, 256, 0, stream>>>(X, Y, Gx, Gy);
  dot_kernel<<<1024, 256, 0, stream>>>((const float4*)Gx, (const float4*)Gy,
                                       acc, cnt, out);
}

// Round 8
// 227.147 us; speedup vs baseline: 1.0386x; 1.0386x over previous
//
#include <hip/hip_runtime.h>
#include <stdint.h>

#define BATCH 8192   // Gram K dimension
#define DIM   2048   // Gram M and N

typedef unsigned char  u8;
typedef unsigned short u16;
typedef unsigned int   u32;

using v8i  = __attribute__((ext_vector_type(8)))  int;
using v16f = __attribute__((ext_vector_type(16))) float;

#if __has_builtin(__builtin_amdgcn_cvt_scalef32_pk_fp4_f32)
#define HW_FP4 1
#endif

// async global->LDS, 16B per lane; dest must be wave-uniform base + lane*16.
__device__ __forceinline__ void gl_lds16(const void* g, void* l) {
  __builtin_amdgcn_global_load_lds(
      (const __attribute__((address_space(1))) u32*)g,
      (__attribute__((address_space(3))) u32*)l, 16, 0, 0);
}

// Fallback f32 -> fp4 e2m1 nibble of (64*x), round-to-nearest.
__device__ __forceinline__ u32 nib4(float x) {
  float xs = x * 64.0f;
  float a  = fabsf(xs);
  u32 n = (u32)(a >= 0.25f) + (u32)(a >= 0.75f) + (u32)(a >= 1.25f) +
          (u32)(a >= 1.75f) + (u32)(a >= 2.5f)  + (u32)(a >= 3.5f)  +
          (u32)(a >= 5.0f);
  return n | (xs < 0.0f ? 8u : 0u);
}

// Pack 4 floats (quant domain = 64*x) into 4 e2m1 nibbles (u16).
__device__ __forceinline__ u16 pack4_fp4(float a, float b, float c, float d) {
#ifdef HW_FP4
  u32 w = __builtin_amdgcn_cvt_scalef32_pk_fp4_f32(0u,  a * 64.0f, b * 64.0f, 1.0f, 0);
  w     = __builtin_amdgcn_cvt_scalef32_pk_fp4_f32(w,   c * 64.0f, d * 64.0f, 1.0f, 1);
  return (u16)w;   // nibble-order differences are k-permutations -> cancel
#else
  return (u16)(nib4(a) | (nib4(b) << 4) | (nib4(c) << 8) | (nib4(d) << 12));
#endif
}

// ---------------------------------------------------------------------------
// Kernel 1: fused transpose + f32->fp4. src [8192 b][2048 d] f32 ->
// dst [2048 d][8192 b-fp4] (4096 B/row). Round-6 proven indexing; round-8
// change: ALL 16 float4 loads hoisted before packing (single vmcnt ramp,
// max memory-level parallelism) instead of 4 load->pack round trips.
// Block 0 zero-inits acc + ticket.
// ---------------------------------------------------------------------------
__global__ __launch_bounds__(256) void tcvt_fp4(
    const float* __restrict__ L, const float* __restrict__ T,
    u8* __restrict__ X, u8* __restrict__ Y,
    float* __restrict__ acc, u32* __restrict__ cnt)
{
  __shared__ u16 ls[64 * 68];   // [d][64 u16 payload + 4 pad]

  const int tid = threadIdx.x;
  if (blockIdx.x == 0 && tid == 0) { *acc = 0.0f; *cnt = 0u; }

  int id = blockIdx.x;
  const float* src;
  u8* dst;
  if (id < 1024) { src = L; dst = X; }
  else           { src = T; dst = Y; id -= 1024; }
  const int d0 = (id & 31) * 64;
  const int b0 = (id >> 5) * 256;

  const int s  = tid & 15;          // d-slot (d = 4s..4s+3)
  const int g  = tid >> 4;          // b row-group
  const int sw = s & 12;

  // Hoisted loads: 16 float4 in flight (64 VGPRs of data).
  float4 f[4][4];
#pragma unroll
  for (int j = 0; j < 4; ++j)
#pragma unroll
    for (int r = 0; r < 4; ++r)
      f[j][r] = *(const float4*)(src + (size_t)(b0 + j * 64 + g * 4 + r) * DIM
                                 + d0 + s * 4);

#pragma unroll
  for (int j = 0; j < 4; ++j) {
    const int w = (j * 16 + g) ^ sw;   // u16 column 0..63
    const float* fp[4] = {(const float*)&f[j][0], (const float*)&f[j][1],
                          (const float*)&f[j][2], (const float*)&f[j][3]};
#pragma unroll
    for (int i = 0; i < 4; ++i)
      ls[(s * 4 + i) * 68 + w] = pack4_fp4(fp[0][i], fp[1][i], fp[2][i], fp[3][i]);
  }
  __syncthreads();

  // Phase B (unchanged): row d = 64 u16 = 128 B fp4; gsw = (d>>4)&3.
#pragma unroll
  for (int j2 = 0; j2 < 2; ++j2) {
    const int d   = (tid >> 3) + j2 * 32;
    const int o8  = tid & 7;
    const int gsw = (d >> 4) & 3;
    const int g1  = (2 * o8)     ^ gsw;
    const int g2  = (2 * o8 + 1) ^ gsw;
    uint2 a = *(const uint2*)&ls[d * 68 + g1 * 4];
    uint2 b = *(const uint2*)&ls[d * 68 + g2 * 4];
    uint4 v = {a.x, a.y, b.x, b.y};
    *(uint4*)(dst + (size_t)(d0 + d) * (BATCH / 2) + (b0 >> 1) + o8 * 16) = v;
  }
}

// ---------------------------------------------------------------------------
// Kernel 2: Gram tile, materialized, MX-fp4, BK=256 (round-8 fix).
// Row stride now 128 B = exactly 32 banks -> the R4-PROVEN swizzle geometry
// (8 chunks/row, chunk p of row r holds global chunk p ^ (r&7)).
// Fragment-read bank start = 4*(r&7): 8 consecutive rows tile all 32 banks
// exactly once -> uniform 4 accesses/bank/half-wave = structural floor.
// (Round-7's 64B rows covered only 16 banks/half-wave -> 3x conflicts.)
// LDS 2 bufs x 2 panels x 16 KB = 64 KB/block, 2 blocks/CU. 32 k-iters.
// ---------------------------------------------------------------------------
__global__ __launch_bounds__(256, 2) void gram_fp4(
    const u8* __restrict__ X, const u8* __restrict__ Y,
    float* __restrict__ Gx, float* __restrict__ Gy)
{
  __shared__ u8 ls[2][2][16384];   // [buf][panel I/J][128 rows x 128 B]

  const int tid = threadIdx.x;
  const int bid = blockIdx.x;
  const int t   = bid & 255;
  const u8*  src = (bid < 256) ? X : Y;
  float*     dst = (bid < 256) ? Gx : Gy;
  const int i0  = (t >> 4) * 128;
  const int j0  = (t & 15) * 128;

  const int wave = tid >> 6;
  const int lane = tid & 63;
  const int wr = (wave >> 1) * 64;
  const int wc = (wave & 1) * 64;
  const int lr = lane & 31;
  const int kh = lane >> 5;          // 16B chunk half within a 32B k-step

  // Staging: 16 KB/panel = 4 rounds x 256 lanes x 16 B; lane-contiguous dst.
  u32 sdst[4], soi[4], soj[4];
#pragma unroll
  for (int rr = 0; rr < 4; ++rr) {
    const int li  = rr * 256 + tid;
    const int row = li >> 3;          // 8 chunks of 16B per 128B row
    const int p   = li & 7;
    const int gc  = p ^ (row & 7);
    sdst[rr] = (u32)(row * 128 + p * 16);
    soi[rr]  = (u32)(i0 + row) * (BATCH / 2) + gc * 16;
    soj[rr]  = (u32)(j0 + row) * (BATCH / 2) + gc * 16;
  }

  // Fragment LDS byte addresses: [half][ks 0..3], one b128 each.
  u32 fa[2][4], fb[2][4];
#pragma unroll
  for (int h = 0; h < 2; ++h) {
    const int ra = wr + h * 32 + lr;
    const int rb = wc + h * 32 + lr;
#pragma unroll
    for (int ks = 0; ks < 4; ++ks) {
      const int c = 2 * ks + kh;      // logical 16B chunk 0..7
      fa[h][ks] = (u32)(ra * 128 + (c ^ (ra & 7)) * 16);
      fb[h][ks] = (u32)(rb * 128 + (c ^ (rb & 7)) * 16);
    }
  }

  v16f acc[2][2] = {};
  const int sc = 0x7F7F7F7F;          // e8m0 = 127 -> scale 1.0

  // Prologue: stage k-iter 0 into buffer 0.
#pragma unroll
  for (int rr = 0; rr < 4; ++rr) {
    gl_lds16(src + soi[rr], &ls[0][0][sdst[rr]]);
    gl_lds16(src + soj[rr], &ls[0][1][sdst[rr]]);
  }

  for (int it = 0; it < 32; ++it) {
    __syncthreads();                  // staging of buf done; buf^1 free
    const int buf = it & 1;
    if (it < 31) {
      const u32 k1 = (u32)(it + 1) * 128;   // 128 B fp4 = 256 k per iter
#pragma unroll
      for (int rr = 0; rr < 4; ++rr) {
        gl_lds16(src + soi[rr] + k1, &ls[buf ^ 1][0][sdst[rr]]);
        gl_lds16(src + soj[rr] + k1, &ls[buf ^ 1][1][sdst[rr]]);
      }
    }
    const u8* pI = ls[buf][0];
    const u8* pJ = ls[buf][1];
#pragma unroll
    for (int ks = 0; ks < 4; ++ks) {
      v8i a[2], b[2];
#pragma unroll
      for (int h = 0; h < 2; ++h) {
        int4 pa = *(const int4*)&pI[fa[h][ks]];
        a[h] = (v8i){pa.x, pa.y, pa.z, pa.w, 0, 0, 0, 0};
        int4 pb = *(const int4*)&pJ[fb[h][ks]];
        b[h] = (v8i){pb.x, pb.y, pb.z, pb.w, 0, 0, 0, 0};
      }
#pragma unroll
      for (int h = 0; h < 2; ++h)
#pragma unroll
        for (int hc = 0; hc < 2; ++hc)
          acc[h][hc] = __builtin_amdgcn_mfma_scale_f32_32x32x64_f8f6f4(
              a[h], b[hc], acc[h][hc], /*cbsz=fp4*/ 4, /*blgp=fp4*/ 4,
              0, sc, 0, sc);
    }
  }

  // Store tile in lane-slot order (both grams identical -> dot invariant).
  float4* o = (float4*)(dst + (size_t)t * 16384);
#pragma unroll
  for (int h = 0; h < 2; ++h)
#pragma unroll
    for (int hc = 0; hc < 2; ++hc)
#pragma unroll
      for (int r4 = 0; r4 < 4; ++r4) {
        float4 v = {acc[h][hc][r4 * 4 + 0], acc[h][hc][r4 * 4 + 1],
                    acc[h][hc][r4 * 4 + 2], acc[h][hc][r4 * 4 + 3]};
        o[((h * 2 + hc) * 4 + r4) * 256 + tid] = v;
      }
}

// ---------------------------------------------------------------------------
// Kernel 3: elementwise dot of the two Grams + fused finalize (ticket).
// ---------------------------------------------------------------------------
__global__ __launch_bounds__(256) void dot_kernel(
    const float4* __restrict__ Gx, const float4* __restrict__ Gy,
    float* __restrict__ d_acc, u32* __restrict__ d_cnt,
    float* __restrict__ out)
{
  __shared__ float red[4];
  const int tid  = threadIdx.x;
  const int lane = tid & 63;
  const int i0   = blockIdx.x * 256 + tid;
  float s = 0.0f;
#pragma unroll
  for (int j = 0; j < 4; ++j) {
    float4 a = Gx[i0 + j * 262144];
    float4 b = Gy[i0 + j * 262144];
    s += a.x * b.x + a.y * b.y + a.z * b.z + a.w * b.w;
  }
#pragma unroll
  for (int off = 32; off > 0; off >>= 1)
    s += __shfl_down(s, off);
  if (lane == 0) red[tid >> 6] = s;
  __syncthreads();
  if (tid == 0) {
    atomicAdd(d_acc, red[0] + red[1] + red[2] + red[3]);
    __threadfence();
    const u32 old = atomicAdd(d_cnt, 1u);
    if (old == 1023u) {                      // last of 1024 blocks
      float S   = atomicAdd(d_acc, 0.0f);    // device-coherent read
      // fidelity = S / (B^2 * 64^4) = S * 2^-50
      float fid = S * 0x1.0p-50f;
      fid = fminf(fmaxf(fid, 0.0f), 1.0f);
      *out = 0.1f * fabsf(fid - 0.95f);
    }
  }
}

extern "C" void kernel_launch(void* const* d_in, const int* in_sizes, int n_in,
                              void* d_out, int out_size, void* d_ws, size_t ws_size,
                              hipStream_t stream) {
  const float* L = (const float*)d_in[0];
  const float* T = (const float*)d_in[1];
  float* out = (float*)d_out;

  const size_t NF4 = (size_t)BATCH * DIM / 2;    // 8,388,608 B per fp4 tensor
  const size_t GEL = (size_t)DIM * DIM;          // 4,194,304 floats per Gram
  u8*    X   = (u8*)d_ws;
  u8*    Y   = (u8*)d_ws + NF4;
  float* Gx  = (float*)((char*)d_ws + 2 * NF4);
  float* Gy  = Gx + GEL;
  float* acc = Gy + GEL;
  u32*   cnt = (u32*)(acc + 1);

  tcvt_fp4<<<2048, 256, 0, stream>>>(L, T, X, Y, acc, cnt);
  gram_fp4<<<512, 256, 0, stream>>>(X, Y, Gx, Gy);
  dot_kernel<<<1024, 256, 0, stream>>>((const float4*)Gx, (const float4*)Gy,
                                       acc, cnt, out);
}